// Round 22
// baseline (93.390 us; speedup 1.0000x reference)
//
#include <hip/hip_runtime.h>
#include <stdint.h>

typedef __bf16 bf16;
typedef __bf16 bf16x8 __attribute__((ext_vector_type(8)));
typedef __bf16 bf16x4 __attribute__((ext_vector_type(4)));
typedef float f32x4 __attribute__((ext_vector_type(4)));
typedef float f32x16 __attribute__((ext_vector_type(16)));
typedef uint32_t u32x4 __attribute__((ext_vector_type(4)));

#define MFMA16x16x32(A, B, C) __builtin_amdgcn_mfma_f32_16x16x32_bf16((A), (B), (C), 0, 0, 0)
#define MFMA32x32x16(A, B, C) __builtin_amdgcn_mfma_f32_32x32x16_bf16((A), (B), (C), 0, 0, 0)
#define SBAR() do { __builtin_amdgcn_s_barrier(); __builtin_amdgcn_sched_barrier(0); } while (0)

__device__ __forceinline__ void gload_lds16(const void* g, void* l) {
  __builtin_amdgcn_global_load_lds((const __attribute__((address_space(1))) void*)g,
                                   (__attribute__((address_space(3))) void*)l,
                                   16, 0, 0);
}

__device__ __forceinline__ float fexp2(float x) { return __builtin_amdgcn_exp2f(x); }

__device__ __forceinline__ uint32_t cvtpk(float a, float b) {
  uint32_t r;
  asm("v_cvt_pk_bf16_f32 %0, %1, %2" : "=v"(r) : "v"(a), "v"(b));
  return r;
}
__device__ __forceinline__ void plswap(uint32_t& a, uint32_t& b) {
  asm volatile("v_permlane32_swap_b32 %0, %1" : "+v"(a), "+v"(b));
}

__device__ __forceinline__ bf16x8 cvt8(float4 a, float4 b) {
  bf16x8 o;
  o[0] = (bf16)a.x; o[1] = (bf16)a.y; o[2] = (bf16)a.z; o[3] = (bf16)a.w;
  o[4] = (bf16)b.x; o[5] = (bf16)b.y; o[6] = (bf16)b.z; o[7] = (bf16)b.w;
  return o;
}

// ---------------- QKV projection with FUSED f32->bf16 cast (validated r15/r18/r19) ---
__global__ __launch_bounds__(256, 2) void qkv128_kernel(
    const float* __restrict__ x1, const float* __restrict__ x2,
    const float* __restrict__ Wq, const float* __restrict__ Wk,
    const float* __restrict__ Wv, bf16* __restrict__ Qw,
    bf16* __restrict__ Kw, bf16* __restrict__ Vtw) {
  __shared__ bf16 As[3][128 * 32];
  __shared__ bf16 Bs[3][128 * 32];
  const int tid = threadIdx.x;
  const int w = tid >> 6, l = tid & 63;
  const int wr = w >> 1, wc = w & 1;
  const int lr = l & 15, lg = l >> 4;
  const int bm = blockIdx.x, bn = blockIdx.y;
  const int K = 512;
  const int sel = bn >> 2, wn = bn & 3;

  const float* A = (sel == 0) ? x1 : x2;
  const float* B = ((sel == 0) ? Wq : (sel == 1) ? Wk : Wv) + (size_t)wn * 128 * K;

  const int c_row = l >> 2;
  const int c_s = l & 3;
  const int sw = (c_s ^ (c_row & 3)) * 8;

  float4 ra0[2][2], ra1[2][2], rb0[2][2], rb1[2][2];

#define ISSUE(t, ra, rb)                                                          \
  {                                                                               \
    _Pragma("unroll") for (int i = 0; i < 2; i++) {                               \
      const int q = w + i * 4;                                                    \
      const float* pa = A + (size_t)(bm * 128 + q * 16 + c_row) * K + (t) * 32 + c_s * 8; \
      ra[i][0] = *reinterpret_cast<const float4*>(pa);                            \
      ra[i][1] = *reinterpret_cast<const float4*>(pa + 4);                        \
      const float* pb = B + (size_t)(q * 16 + c_row) * K + (t) * 32 + c_s * 8;    \
      rb[i][0] = *reinterpret_cast<const float4*>(pb);                            \
      rb[i][1] = *reinterpret_cast<const float4*>(pb + 4);                        \
    }                                                                             \
  }
#define COMMIT(bb, ra, rb)                                                        \
  {                                                                               \
    _Pragma("unroll") for (int i = 0; i < 2; i++) {                               \
      const int q = w + i * 4;                                                    \
      *reinterpret_cast<bf16x8*>(&As[bb][q * 512 + c_row * 32 + sw]) = cvt8(ra[i][0], ra[i][1]); \
      *reinterpret_cast<bf16x8*>(&Bs[bb][q * 512 + c_row * 32 + sw]) = cvt8(rb[i][0], rb[i][1]); \
    }                                                                             \
  }

  f32x4 acc[4][4] = {};
  const int swz = (lr & 3) * 8;

  auto compute = [&](int cur) {
    bf16x8 a[4], b[4];
#pragma unroll
    for (int mi = 0; mi < 4; mi++)
      a[mi] = *reinterpret_cast<const bf16x8*>(
          &As[cur][(wr * 64 + mi * 16 + lr) * 32 + (lg * 8 ^ swz)]);
#pragma unroll
    for (int ni = 0; ni < 4; ni++)
      b[ni] = *reinterpret_cast<const bf16x8*>(
          &Bs[cur][(wc * 64 + ni * 16 + lr) * 32 + (lg * 8 ^ swz)]);
#pragma unroll
    for (int mi = 0; mi < 4; mi++)
#pragma unroll
      for (int ni = 0; ni < 4; ni++)
        acc[mi][ni] = MFMA16x16x32(a[mi], b[ni], acc[mi][ni]);
  };

  ISSUE(0, ra0, rb0);
  ISSUE(1, ra1, rb1);
  asm volatile("s_waitcnt vmcnt(8)" ::: "memory");
  COMMIT(0, ra0, rb0);
  asm volatile("s_waitcnt lgkmcnt(0)" ::: "memory");
  SBAR();

  const int NT = 16;
  for (int t = 0; t < NT; t += 2) {
    if (t + 2 < NT) ISSUE(t + 2, ra0, rb0);
    compute(t % 3);
    {
      if (t + 2 < NT) asm volatile("s_waitcnt vmcnt(8)" ::: "memory");
      else            asm volatile("s_waitcnt vmcnt(0)" ::: "memory");
      COMMIT((t + 1) % 3, ra1, rb1);
      asm volatile("s_waitcnt lgkmcnt(0)" ::: "memory");
      SBAR();
    }
    if (t + 3 < NT) ISSUE(t + 3, ra1, rb1);
    compute((t + 1) % 3);
    if (t + 2 < NT) {
      if (t + 3 < NT) asm volatile("s_waitcnt vmcnt(8)" ::: "memory");
      else            asm volatile("s_waitcnt vmcnt(0)" ::: "memory");
      COMMIT((t + 2) % 3, ra0, rb0);
      asm volatile("s_waitcnt lgkmcnt(0)" ::: "memory");
      SBAR();
    }
  }
#undef ISSUE
#undef COMMIT

  const float scale = (sel == 0) ? 0.18033688011112f : 1.0f;
#pragma unroll
  for (int mi = 0; mi < 4; mi++) {
    const int m0 = bm * 128 + wr * 64 + mi * 16 + lg * 4;
#pragma unroll
    for (int ni = 0; ni < 4; ni++) {
      const int gn = wn * 128 + wc * 64 + ni * 16 + lr;
      if (sel < 2) {
        bf16* dst = (sel == 0) ? Qw : Kw;
#pragma unroll
        for (int r = 0; r < 4; r++) {
          const int m = m0 + r;
          size_t d = (size_t)((m >> 11) * 8 + (gn >> 6)) * 131072 + (size_t)(m & 2047) * 64 + (gn & 63);
          dst[d] = (bf16)(acc[mi][ni][r] * scale);
        }
      } else {
        bf16x4 pv;
#pragma unroll
        for (int r = 0; r < 4; r++) pv[r] = (bf16)acc[mi][ni][r];
        size_t base = ((size_t)(m0 >> 11) * 512 + gn) * 2048 + (m0 & 2047);
        *reinterpret_cast<bf16x4*>(Vtw + base) = pv;
      }
    }
  }
}

// ---------------- out projection (validated) ----------------
__global__ __launch_bounds__(256, 4) void outproj_kernel(
    const bf16* __restrict__ A0, const float* __restrict__ W0,
    float* __restrict__ C0, const float* __restrict__ bias) {
  __shared__ bf16 As[3][128 * 32];
  __shared__ bf16 Bs[2][64 * 32];
  const int tid = threadIdx.x;
  const int w = tid >> 6, l = tid & 63;
  const int wr = w >> 1, wc = w & 1;
  const int lr = l & 15, lg = l >> 4;
  const int bm = blockIdx.x, bn = blockIdx.y;
  const int K = 512;

  const float* Bf = W0 + (size_t)bn * 64 * K;
  const int c_row = l >> 2;
  const int c_s = l & 3;
  const int sw = (c_s ^ (c_row & 3)) * 8;

  float4 lb[2][2];
  auto issue_A = [&](int t, int bb) {
#pragma unroll
    for (int i = 0; i < 2; i++) {
      const int q = w + i * 4;
      gload_lds16(A0 + (size_t)(bm * 128 + q * 16 + c_row) * K + t * 32 + sw, &As[bb][q * 512]);
    }
  };
  auto issue_B = [&](int t, int s) {
    const float* pb = Bf + (size_t)(w * 16 + c_row) * K + t * 32 + c_s * 8;
    lb[s][0] = *reinterpret_cast<const float4*>(pb);
    lb[s][1] = *reinterpret_cast<const float4*>(pb + 4);
  };
  auto commit_B = [&](int s, int bb) {
    *reinterpret_cast<bf16x8*>(&Bs[bb][w * 512 + c_row * 32 + sw]) = cvt8(lb[s][0], lb[s][1]);
  };

  f32x4 acc[4][2] = {};
  const int swz = (lr & 3) * 8;

  issue_A(0, 0); issue_B(0, 0);
  issue_A(1, 1); issue_B(1, 1);
  asm volatile("s_waitcnt vmcnt(4)" ::: "memory");
  commit_B(0, 0);
  asm volatile("s_waitcnt lgkmcnt(0)" ::: "memory");
  SBAR();

  const int NT = 16;
  for (int t = 0; t < NT; t++) {
    if (t + 2 < NT) { issue_A(t + 2, (t + 2) % 3); issue_B(t + 2, t & 1); }

    bf16x8 a[4], b[2];
    const int cur = t % 3;
#pragma unroll
    for (int mi = 0; mi < 4; mi++)
      a[mi] = *reinterpret_cast<const bf16x8*>(
          &As[cur][(wr * 64 + mi * 16 + lr) * 32 + (lg * 8 ^ swz)]);
#pragma unroll
    for (int ni = 0; ni < 2; ni++)
      b[ni] = *reinterpret_cast<const bf16x8*>(
          &Bs[t & 1][(wc * 32 + ni * 16 + lr) * 32 + (lg * 8 ^ swz)]);
#pragma unroll
    for (int mi = 0; mi < 4; mi++)
#pragma unroll
      for (int ni = 0; ni < 2; ni++)
        acc[mi][ni] = MFMA16x16x32(a[mi], b[ni], acc[mi][ni]);

    if (t + 1 < NT) {
      if (t + 2 < NT) asm volatile("s_waitcnt vmcnt(4)" ::: "memory");
      else            asm volatile("s_waitcnt vmcnt(0)" ::: "memory");
      commit_B((t + 1) & 1, (t + 1) & 1);
      asm volatile("s_waitcnt lgkmcnt(0)" ::: "memory");
      SBAR();
    }
  }

#pragma unroll
  for (int mi = 0; mi < 4; mi++) {
    const int m0 = bm * 128 + wr * 64 + mi * 16 + lg * 4;
#pragma unroll
    for (int ni = 0; ni < 2; ni++) {
      const int gn = bn * 64 + wc * 32 + ni * 16 + lr;
      const float bv = bias[gn];
#pragma unroll
      for (int r = 0; r < 4; r++)
        C0[(size_t)(m0 + r) * 512 + gn] = acc[mi][ni][r] + bv;
    }
  }
}

// ---------------- flash attention: r19 + interleaved stage placement ----------------
// Block: 512 thr = 8 waves = 4 q-groups(64 q) x 2 kv-halves; 256 q/block; grid 256.
// Ring-4, TWO tiles per barrier interval, full vmcnt(0) drain before every barrier.
// Change vs r19: stage(t1+2) issued BETWEEN the two tilebodies (spreads VMEM issue
// under tilebody(t0)'s compute). Buffer (t0+3)&3 is written, t0&3/(t0+1)&3 read —
// disjoint mod 4; same drain semantics. (Counted vmcnt excluded — failed r16/r17;
// ring-8 excluded — spilled r20; setprio excluded — r15.)
__global__ __launch_bounds__(512, 1) void attn_kernel(
    const bf16* __restrict__ Q, const bf16* __restrict__ Kk,
    const bf16* __restrict__ Vt, bf16* __restrict__ AO) {
  __shared__ bf16 KV[2][4][64 * 64];  // [K|V][ring4][tile] = 64KB
  __shared__ float cls[4][2][32];     // lsum combine

  const int tid = threadIdx.x;
  const int w = tid >> 6, l = tid & 63;  // w 0..7
  const int q32 = l & 31;
  const int h = l >> 5;
  const int qg = w >> 1, kvh = w & 1;
  const int l7 = l & 7;

  // XCD-aware decode: grid 256, lin&7 = XCD; 4 bh per XCD -> K/V L2-resident
  const int lin = blockIdx.x;
  const int xcd = lin & 7;
  const int m = lin >> 3;            // 0..31
  const int bh = xcd * 4 + (m & 3);
  const int qb = m >> 2;             // 0..7
  const int b = bh >> 3, hd = bh & 7;

  const bf16* Qb = Q + (size_t)bh * 131072;
  const bf16* Kb = Kk + (size_t)bh * 131072;
  const bf16* Vb = Vt + (size_t)bh * 131072;

  const int q0 = qb * 256 + qg * 64;

  // Q B-frags: sub-block i, col q = q32, k = d = ks*16 + h*8 + j
  bf16x8 qf[2][4];
#pragma unroll
  for (int i = 0; i < 2; i++)
#pragma unroll
    for (int ks = 0; ks < 4; ks++)
      qf[i][ks] = *reinterpret_cast<const bf16x8*>(
          Qb + (size_t)(q0 + i * 32 + q32) * 64 + ks * 16 + h * 8);

  // staging: wave w stages K-chunk w and V-chunk w (8 rows x 64 each, 1KB)
  const int crow = l >> 3;
  const int scol = ((l & 7) ^ crow) * 8;
  auto stage = [&](int kv0, int bb) {
    const int row = w * 8 + crow;
    gload_lds16(Kb + (size_t)(kv0 + row) * 64 + scol, &KV[0][bb][w * 512]);
    gload_lds16(Vb + (size_t)row * 2048 + kv0 + scol, &KV[1][bb][w * 512]);
  };

  f32x16 oacc[2][2] = {};  // [i][db]
  float lsum[2] = {0.f, 0.f};

  // per-64kv-tile compute (r14/r18/r19-exact indexing)
  auto tilebody = [&](int cur) {
    bf16x8 kb[4];
#pragma unroll
    for (int ks = 0; ks < 4; ks++)
      kb[ks] = *reinterpret_cast<const bf16x8*>(
          &KV[0][cur][(kvh * 32 + q32) * 64 + (((ks * 2 + h) ^ l7) * 8)]);

    bf16x8 pa[2][2];
#pragma unroll
    for (int i = 0; i < 2; i++) {
      f32x16 st = {};
#pragma unroll
      for (int ks = 0; ks < 4; ks++)
        st = MFMA32x32x16(kb[ks], qf[i][ks], st);

      float e[16];
#pragma unroll
      for (int r = 0; r < 16; r++) {
        e[r] = fexp2(st[r]);
        lsum[i] += e[r];
      }
      uint32_t Qp[8];
#pragma unroll
      for (int p2 = 0; p2 < 8; p2++) Qp[p2] = cvtpk(e[2 * p2], e[2 * p2 + 1]);
      plswap(Qp[0], Qp[2]);
      plswap(Qp[1], Qp[3]);
      plswap(Qp[4], Qp[6]);
      plswap(Qp[5], Qp[7]);
      pa[i][0] = __builtin_bit_cast(bf16x8, (u32x4){Qp[0], Qp[1], Qp[2], Qp[3]});
      pa[i][1] = __builtin_bit_cast(bf16x8, (u32x4){Qp[4], Qp[5], Qp[6], Qp[7]});
    }

    bf16x8 vb[2][2];
#pragma unroll
    for (int kst = 0; kst < 2; kst++)
#pragma unroll
      for (int db = 0; db < 2; db++)
        vb[kst][db] = *reinterpret_cast<const bf16x8*>(
            &KV[1][cur][(db * 32 + q32) * 64 + (((kvh * 4 + kst * 2 + h) ^ l7) * 8)]);

#pragma unroll
    for (int i = 0; i < 2; i++)
#pragma unroll
      for (int kst = 0; kst < 2; kst++)
#pragma unroll
        for (int db = 0; db < 2; db++)
          oacc[i][db] = MFMA32x32x16(pa[i][kst], vb[kst][db], oacc[i][db]);
  };

  // prologue: stage tiles 0,1; full drain
  stage(0, 0);
  stage(64, 1);
  asm volatile("s_waitcnt vmcnt(0)" ::: "memory");
  SBAR();

  for (int p = 0; p < 16; p++) {
    const int t0 = 2 * p, t1 = 2 * p + 1;
    if (p < 15) stage((t0 + 2) * 64, (t0 + 2) & 3);
    tilebody(t0 & 3);
    if (p < 15) stage((t1 + 2) * 64, (t1 + 2) & 3);
    tilebody(t1 & 3);
    if (p < 15) {
      asm volatile("s_waitcnt vmcnt(0) lgkmcnt(0)" ::: "memory");
      SBAR();
    }
  }

  // lanes l and l+32 hold partials of the same q (within this wave's kv-half)
#pragma unroll
  for (int i = 0; i < 2; i++) lsum[i] += __shfl_xor(lsum[i], 32);

  // combine kv-halves via dead K/V LDS (first 32KB), two passes (i=0, i=1)
  float* cb = (float*)&KV[0][0][0];
  __syncthreads();
  if (kvh == 1 && l < 32) {
    cls[qg][0][q32] = lsum[0];
    cls[qg][1][q32] = lsum[1];
  }
#pragma unroll
  for (int i = 0; i < 2; i++) {
    if (kvh == 1) {
#pragma unroll
      for (int db = 0; db < 2; db++)
#pragma unroll
        for (int r = 0; r < 16; r++)
          cb[((qg * 2 + db) * 16 + r) * 64 + l] = oacc[i][db][r];
    }
    __syncthreads();
    if (kvh == 0) {
#pragma unroll
      for (int db = 0; db < 2; db++)
#pragma unroll
        for (int r = 0; r < 16; r++)
          oacc[i][db][r] += cb[((qg * 2 + db) * 16 + r) * 64 + l];
    }
    __syncthreads();
  }

  if (kvh == 0) {
#pragma unroll
    for (int i = 0; i < 2; i++) {
      lsum[i] += cls[qg][i][q32];
      float inv[16];
#pragma unroll
      for (int r = 0; r < 16; r++) {
        const int qv = (r & 3) + 8 * (r >> 2) + 4 * h;
        inv[r] = 1.f / __shfl(lsum[i], qv);
      }
#pragma unroll
      for (int db = 0; db < 2; db++) {
#pragma unroll
        for (int r = 0; r < 16; r++) {
          const int qv = (r & 3) + 8 * (r >> 2) + 4 * h;
          AO[(size_t)(b * 2048 + q0 + i * 32 + qv) * 512 + hd * 64 + db * 32 + q32] =
              (bf16)(oacc[i][db][r] * inv[r]);
        }
      }
    }
  }
}

// ---------------- launch ----------------
extern "C" void kernel_launch(void* const* d_in, const int* in_sizes, int n_in,
                              void* d_out, int out_size, void* d_ws, size_t ws_size,
                              hipStream_t stream) {
  (void)in_sizes; (void)n_in; (void)out_size; (void)ws_size;
  const float* x1 = (const float*)d_in[0];
  const float* x2 = (const float*)d_in[1];
  const float* Wq = (const float*)d_in[2];
  const float* Wk = (const float*)d_in[3];
  const float* Wv = (const float*)d_in[4];
  const float* Wo = (const float*)d_in[5];
  const float* bo = (const float*)d_in[6];

  uint8_t* ws = (uint8_t*)d_ws;
  bf16* AO  = (bf16*)(ws + 0);          // [8192][512]
  bf16* Qws = (bf16*)(ws + 18874368);   // [b][h][s][64]
  bf16* Kws = (bf16*)(ws + 27262976);   // [b][h][s][64]
  bf16* Vtw = (bf16*)(ws + 35651584);   // [b][h][64][s]

  qkv128_kernel<<<dim3(64, 12), 256, 0, stream>>>(x1, x2, Wq, Wk, Wv, Qws, Kws, Vtw);

  attn_kernel<<<256, 512, 0, stream>>>(Qws, Kws, Vtw, AO);

  outproj_kernel<<<dim3(64, 8), 256, 0, stream>>>(AO, Wo, (float*)d_out, bo);
}

// Round 23
// 93.113 us; speedup vs baseline: 1.0030x; 1.0030x over previous
//
#include <hip/hip_runtime.h>
#include <stdint.h>

typedef __bf16 bf16;
typedef __bf16 bf16x8 __attribute__((ext_vector_type(8)));
typedef __bf16 bf16x4 __attribute__((ext_vector_type(4)));
typedef float f32x4 __attribute__((ext_vector_type(4)));
typedef float f32x16 __attribute__((ext_vector_type(16)));
typedef uint32_t u32x4 __attribute__((ext_vector_type(4)));

#define MFMA16x16x32(A, B, C) __builtin_amdgcn_mfma_f32_16x16x32_bf16((A), (B), (C), 0, 0, 0)
#define MFMA32x32x16(A, B, C) __builtin_amdgcn_mfma_f32_32x32x16_bf16((A), (B), (C), 0, 0, 0)
#define SBAR() do { __builtin_amdgcn_s_barrier(); __builtin_amdgcn_sched_barrier(0); } while (0)

__device__ __forceinline__ void gload_lds16(const void* g, void* l) {
  __builtin_amdgcn_global_load_lds((const __attribute__((address_space(1))) void*)g,
                                   (__attribute__((address_space(3))) void*)l,
                                   16, 0, 0);
}

__device__ __forceinline__ float fexp2(float x) { return __builtin_amdgcn_exp2f(x); }

__device__ __forceinline__ uint32_t cvtpk(float a, float b) {
  uint32_t r;
  asm("v_cvt_pk_bf16_f32 %0, %1, %2" : "=v"(r) : "v"(a), "v"(b));
  return r;
}
__device__ __forceinline__ void plswap(uint32_t& a, uint32_t& b) {
  asm volatile("v_permlane32_swap_b32 %0, %1" : "+v"(a), "+v"(b));
}

__device__ __forceinline__ bf16x8 cvt8(float4 a, float4 b) {
  bf16x8 o;
  o[0] = (bf16)a.x; o[1] = (bf16)a.y; o[2] = (bf16)a.z; o[3] = (bf16)a.w;
  o[4] = (bf16)b.x; o[5] = (bf16)b.y; o[6] = (bf16)b.z; o[7] = (bf16)b.w;
  return o;
}

// ---------------- QKV projection with FUSED f32->bf16 cast (validated r15/r18/r19) ---
__global__ __launch_bounds__(256, 2) void qkv128_kernel(
    const float* __restrict__ x1, const float* __restrict__ x2,
    const float* __restrict__ Wq, const float* __restrict__ Wk,
    const float* __restrict__ Wv, bf16* __restrict__ Qw,
    bf16* __restrict__ Kw, bf16* __restrict__ Vtw) {
  __shared__ bf16 As[3][128 * 32];
  __shared__ bf16 Bs[3][128 * 32];
  const int tid = threadIdx.x;
  const int w = tid >> 6, l = tid & 63;
  const int wr = w >> 1, wc = w & 1;
  const int lr = l & 15, lg = l >> 4;
  const int bm = blockIdx.x, bn = blockIdx.y;
  const int K = 512;
  const int sel = bn >> 2, wn = bn & 3;

  const float* A = (sel == 0) ? x1 : x2;
  const float* B = ((sel == 0) ? Wq : (sel == 1) ? Wk : Wv) + (size_t)wn * 128 * K;

  const int c_row = l >> 2;
  const int c_s = l & 3;
  const int sw = (c_s ^ (c_row & 3)) * 8;

  float4 ra0[2][2], ra1[2][2], rb0[2][2], rb1[2][2];

#define ISSUE(t, ra, rb)                                                          \
  {                                                                               \
    _Pragma("unroll") for (int i = 0; i < 2; i++) {                               \
      const int q = w + i * 4;                                                    \
      const float* pa = A + (size_t)(bm * 128 + q * 16 + c_row) * K + (t) * 32 + c_s * 8; \
      ra[i][0] = *reinterpret_cast<const float4*>(pa);                            \
      ra[i][1] = *reinterpret_cast<const float4*>(pa + 4);                        \
      const float* pb = B + (size_t)(q * 16 + c_row) * K + (t) * 32 + c_s * 8;    \
      rb[i][0] = *reinterpret_cast<const float4*>(pb);                            \
      rb[i][1] = *reinterpret_cast<const float4*>(pb + 4);                        \
    }                                                                             \
  }
#define COMMIT(bb, ra, rb)                                                        \
  {                                                                               \
    _Pragma("unroll") for (int i = 0; i < 2; i++) {                               \
      const int q = w + i * 4;                                                    \
      *reinterpret_cast<bf16x8*>(&As[bb][q * 512 + c_row * 32 + sw]) = cvt8(ra[i][0], ra[i][1]); \
      *reinterpret_cast<bf16x8*>(&Bs[bb][q * 512 + c_row * 32 + sw]) = cvt8(rb[i][0], rb[i][1]); \
    }                                                                             \
  }

  f32x4 acc[4][4] = {};
  const int swz = (lr & 3) * 8;

  auto compute = [&](int cur) {
    bf16x8 a[4], b[4];
#pragma unroll
    for (int mi = 0; mi < 4; mi++)
      a[mi] = *reinterpret_cast<const bf16x8*>(
          &As[cur][(wr * 64 + mi * 16 + lr) * 32 + (lg * 8 ^ swz)]);
#pragma unroll
    for (int ni = 0; ni < 4; ni++)
      b[ni] = *reinterpret_cast<const bf16x8*>(
          &Bs[cur][(wc * 64 + ni * 16 + lr) * 32 + (lg * 8 ^ swz)]);
#pragma unroll
    for (int mi = 0; mi < 4; mi++)
#pragma unroll
      for (int ni = 0; ni < 4; ni++)
        acc[mi][ni] = MFMA16x16x32(a[mi], b[ni], acc[mi][ni]);
  };

  ISSUE(0, ra0, rb0);
  ISSUE(1, ra1, rb1);
  asm volatile("s_waitcnt vmcnt(8)" ::: "memory");
  COMMIT(0, ra0, rb0);
  asm volatile("s_waitcnt lgkmcnt(0)" ::: "memory");
  SBAR();

  const int NT = 16;
  for (int t = 0; t < NT; t += 2) {
    if (t + 2 < NT) ISSUE(t + 2, ra0, rb0);
    compute(t % 3);
    {
      if (t + 2 < NT) asm volatile("s_waitcnt vmcnt(8)" ::: "memory");
      else            asm volatile("s_waitcnt vmcnt(0)" ::: "memory");
      COMMIT((t + 1) % 3, ra1, rb1);
      asm volatile("s_waitcnt lgkmcnt(0)" ::: "memory");
      SBAR();
    }
    if (t + 3 < NT) ISSUE(t + 3, ra1, rb1);
    compute((t + 1) % 3);
    if (t + 2 < NT) {
      if (t + 3 < NT) asm volatile("s_waitcnt vmcnt(8)" ::: "memory");
      else            asm volatile("s_waitcnt vmcnt(0)" ::: "memory");
      COMMIT((t + 2) % 3, ra0, rb0);
      asm volatile("s_waitcnt lgkmcnt(0)" ::: "memory");
      SBAR();
    }
  }
#undef ISSUE
#undef COMMIT

  const float scale = (sel == 0) ? 0.18033688011112f : 1.0f;
#pragma unroll
  for (int mi = 0; mi < 4; mi++) {
    const int m0 = bm * 128 + wr * 64 + mi * 16 + lg * 4;
#pragma unroll
    for (int ni = 0; ni < 4; ni++) {
      const int gn = wn * 128 + wc * 64 + ni * 16 + lr;
      if (sel < 2) {
        bf16* dst = (sel == 0) ? Qw : Kw;
#pragma unroll
        for (int r = 0; r < 4; r++) {
          const int m = m0 + r;
          size_t d = (size_t)((m >> 11) * 8 + (gn >> 6)) * 131072 + (size_t)(m & 2047) * 64 + (gn & 63);
          dst[d] = (bf16)(acc[mi][ni][r] * scale);
        }
      } else {
        bf16x4 pv;
#pragma unroll
        for (int r = 0; r < 4; r++) pv[r] = (bf16)acc[mi][ni][r];
        size_t base = ((size_t)(m0 >> 11) * 512 + gn) * 2048 + (m0 & 2047);
        *reinterpret_cast<bf16x4*>(Vtw + base) = pv;
      }
    }
  }
}

// ---------------- out projection (validated) ----------------
__global__ __launch_bounds__(256, 4) void outproj_kernel(
    const bf16* __restrict__ A0, const float* __restrict__ W0,
    float* __restrict__ C0, const float* __restrict__ bias) {
  __shared__ bf16 As[3][128 * 32];
  __shared__ bf16 Bs[2][64 * 32];
  const int tid = threadIdx.x;
  const int w = tid >> 6, l = tid & 63;
  const int wr = w >> 1, wc = w & 1;
  const int lr = l & 15, lg = l >> 4;
  const int bm = blockIdx.x, bn = blockIdx.y;
  const int K = 512;

  const float* Bf = W0 + (size_t)bn * 64 * K;
  const int c_row = l >> 2;
  const int c_s = l & 3;
  const int sw = (c_s ^ (c_row & 3)) * 8;

  float4 lb[2][2];
  auto issue_A = [&](int t, int bb) {
#pragma unroll
    for (int i = 0; i < 2; i++) {
      const int q = w + i * 4;
      gload_lds16(A0 + (size_t)(bm * 128 + q * 16 + c_row) * K + t * 32 + sw, &As[bb][q * 512]);
    }
  };
  auto issue_B = [&](int t, int s) {
    const float* pb = Bf + (size_t)(w * 16 + c_row) * K + t * 32 + c_s * 8;
    lb[s][0] = *reinterpret_cast<const float4*>(pb);
    lb[s][1] = *reinterpret_cast<const float4*>(pb + 4);
  };
  auto commit_B = [&](int s, int bb) {
    *reinterpret_cast<bf16x8*>(&Bs[bb][w * 512 + c_row * 32 + sw]) = cvt8(lb[s][0], lb[s][1]);
  };

  f32x4 acc[4][2] = {};
  const int swz = (lr & 3) * 8;

  issue_A(0, 0); issue_B(0, 0);
  issue_A(1, 1); issue_B(1, 1);
  asm volatile("s_waitcnt vmcnt(4)" ::: "memory");
  commit_B(0, 0);
  asm volatile("s_waitcnt lgkmcnt(0)" ::: "memory");
  SBAR();

  const int NT = 16;
  for (int t = 0; t < NT; t++) {
    if (t + 2 < NT) { issue_A(t + 2, (t + 2) % 3); issue_B(t + 2, t & 1); }

    bf16x8 a[4], b[2];
    const int cur = t % 3;
#pragma unroll
    for (int mi = 0; mi < 4; mi++)
      a[mi] = *reinterpret_cast<const bf16x8*>(
          &As[cur][(wr * 64 + mi * 16 + lr) * 32 + (lg * 8 ^ swz)]);
#pragma unroll
    for (int ni = 0; ni < 2; ni++)
      b[ni] = *reinterpret_cast<const bf16x8*>(
          &Bs[t & 1][(wc * 32 + ni * 16 + lr) * 32 + (lg * 8 ^ swz)]);
#pragma unroll
    for (int mi = 0; mi < 4; mi++)
#pragma unroll
      for (int ni = 0; ni < 2; ni++)
        acc[mi][ni] = MFMA16x16x32(a[mi], b[ni], acc[mi][ni]);

    if (t + 1 < NT) {
      if (t + 2 < NT) asm volatile("s_waitcnt vmcnt(4)" ::: "memory");
      else            asm volatile("s_waitcnt vmcnt(0)" ::: "memory");
      commit_B((t + 1) & 1, (t + 1) & 1);
      asm volatile("s_waitcnt lgkmcnt(0)" ::: "memory");
      SBAR();
    }
  }

#pragma unroll
  for (int mi = 0; mi < 4; mi++) {
    const int m0 = bm * 128 + wr * 64 + mi * 16 + lg * 4;
#pragma unroll
    for (int ni = 0; ni < 2; ni++) {
      const int gn = bn * 64 + wc * 32 + ni * 16 + lr;
      const float bv = bias[gn];
#pragma unroll
      for (int r = 0; r < 4; r++)
        C0[(size_t)(m0 + r) * 512 + gn] = acc[mi][ni][r] + bv;
    }
  }
}

// ---------------- flash attention: r19-exact (best validated: 49.2us) ----------------
// Block: 512 thr = 8 waves = 4 q-groups(64 q) x 2 kv-halves; 256 q/block; grid 256.
// Ring-4, TWO tiles per barrier interval, back-to-back pair staging (r22's interleave
// was neutral/worse), full vmcnt(0) drain before every barrier.
// Excluded by experiment: counted vmcnt (r16/r17 correctness), ring-8 (r20 spill),
// setprio (r15 -3us), KVBLK=128 (r16 correctness), direct-global K/V (r9 2.4x).
__global__ __launch_bounds__(512, 1) void attn_kernel(
    const bf16* __restrict__ Q, const bf16* __restrict__ Kk,
    const bf16* __restrict__ Vt, bf16* __restrict__ AO) {
  __shared__ bf16 KV[2][4][64 * 64];  // [K|V][ring4][tile] = 64KB
  __shared__ float cls[4][2][32];     // lsum combine

  const int tid = threadIdx.x;
  const int w = tid >> 6, l = tid & 63;  // w 0..7
  const int q32 = l & 31;
  const int h = l >> 5;
  const int qg = w >> 1, kvh = w & 1;
  const int l7 = l & 7;

  // XCD-aware decode: grid 256, lin&7 = XCD; 4 bh per XCD -> K/V L2-resident
  const int lin = blockIdx.x;
  const int xcd = lin & 7;
  const int m = lin >> 3;            // 0..31
  const int bh = xcd * 4 + (m & 3);
  const int qb = m >> 2;             // 0..7
  const int b = bh >> 3, hd = bh & 7;

  const bf16* Qb = Q + (size_t)bh * 131072;
  const bf16* Kb = Kk + (size_t)bh * 131072;
  const bf16* Vb = Vt + (size_t)bh * 131072;

  const int q0 = qb * 256 + qg * 64;

  // Q B-frags: sub-block i, col q = q32, k = d = ks*16 + h*8 + j
  bf16x8 qf[2][4];
#pragma unroll
  for (int i = 0; i < 2; i++)
#pragma unroll
    for (int ks = 0; ks < 4; ks++)
      qf[i][ks] = *reinterpret_cast<const bf16x8*>(
          Qb + (size_t)(q0 + i * 32 + q32) * 64 + ks * 16 + h * 8);

  // staging: wave w stages K-chunk w and V-chunk w (8 rows x 64 each, 1KB)
  const int crow = l >> 3;
  const int scol = ((l & 7) ^ crow) * 8;
  auto stage = [&](int kv0, int bb) {
    const int row = w * 8 + crow;
    gload_lds16(Kb + (size_t)(kv0 + row) * 64 + scol, &KV[0][bb][w * 512]);
    gload_lds16(Vb + (size_t)row * 2048 + kv0 + scol, &KV[1][bb][w * 512]);
  };

  f32x16 oacc[2][2] = {};  // [i][db]
  float lsum[2] = {0.f, 0.f};

  // per-64kv-tile compute (r14/r18/r19-exact indexing)
  auto tilebody = [&](int cur) {
    bf16x8 kb[4];
#pragma unroll
    for (int ks = 0; ks < 4; ks++)
      kb[ks] = *reinterpret_cast<const bf16x8*>(
          &KV[0][cur][(kvh * 32 + q32) * 64 + (((ks * 2 + h) ^ l7) * 8)]);

    bf16x8 pa[2][2];
#pragma unroll
    for (int i = 0; i < 2; i++) {
      f32x16 st = {};
#pragma unroll
      for (int ks = 0; ks < 4; ks++)
        st = MFMA32x32x16(kb[ks], qf[i][ks], st);

      float e[16];
#pragma unroll
      for (int r = 0; r < 16; r++) {
        e[r] = fexp2(st[r]);
        lsum[i] += e[r];
      }
      uint32_t Qp[8];
#pragma unroll
      for (int p2 = 0; p2 < 8; p2++) Qp[p2] = cvtpk(e[2 * p2], e[2 * p2 + 1]);
      plswap(Qp[0], Qp[2]);
      plswap(Qp[1], Qp[3]);
      plswap(Qp[4], Qp[6]);
      plswap(Qp[5], Qp[7]);
      pa[i][0] = __builtin_bit_cast(bf16x8, (u32x4){Qp[0], Qp[1], Qp[2], Qp[3]});
      pa[i][1] = __builtin_bit_cast(bf16x8, (u32x4){Qp[4], Qp[5], Qp[6], Qp[7]});
    }

    bf16x8 vb[2][2];
#pragma unroll
    for (int kst = 0; kst < 2; kst++)
#pragma unroll
      for (int db = 0; db < 2; db++)
        vb[kst][db] = *reinterpret_cast<const bf16x8*>(
            &KV[1][cur][(db * 32 + q32) * 64 + (((kvh * 4 + kst * 2 + h) ^ l7) * 8)]);

#pragma unroll
    for (int i = 0; i < 2; i++)
#pragma unroll
      for (int kst = 0; kst < 2; kst++)
#pragma unroll
        for (int db = 0; db < 2; db++)
          oacc[i][db] = MFMA32x32x16(pa[i][kst], vb[kst][db], oacc[i][db]);
  };

  // prologue: stage tiles 0,1; full drain
  stage(0, 0);
  stage(64, 1);
  asm volatile("s_waitcnt vmcnt(0)" ::: "memory");
  SBAR();

  for (int p = 0; p < 16; p++) {
    const int t0 = 2 * p, t1 = 2 * p + 1;
    if (p < 15) {
      stage((t0 + 2) * 64, (t0 + 2) & 3);
      stage((t1 + 2) * 64, (t1 + 2) & 3);
    }
    tilebody(t0 & 3);
    tilebody(t1 & 3);
    if (p < 15) {
      asm volatile("s_waitcnt vmcnt(0) lgkmcnt(0)" ::: "memory");
      SBAR();
    }
  }

  // lanes l and l+32 hold partials of the same q (within this wave's kv-half)
#pragma unroll
  for (int i = 0; i < 2; i++) lsum[i] += __shfl_xor(lsum[i], 32);

  // combine kv-halves via dead K/V LDS (first 32KB), two passes (i=0, i=1)
  float* cb = (float*)&KV[0][0][0];
  __syncthreads();
  if (kvh == 1 && l < 32) {
    cls[qg][0][q32] = lsum[0];
    cls[qg][1][q32] = lsum[1];
  }
#pragma unroll
  for (int i = 0; i < 2; i++) {
    if (kvh == 1) {
#pragma unroll
      for (int db = 0; db < 2; db++)
#pragma unroll
        for (int r = 0; r < 16; r++)
          cb[((qg * 2 + db) * 16 + r) * 64 + l] = oacc[i][db][r];
    }
    __syncthreads();
    if (kvh == 0) {
#pragma unroll
      for (int db = 0; db < 2; db++)
#pragma unroll
        for (int r = 0; r < 16; r++)
          oacc[i][db][r] += cb[((qg * 2 + db) * 16 + r) * 64 + l];
    }
    __syncthreads();
  }

  if (kvh == 0) {
#pragma unroll
    for (int i = 0; i < 2; i++) {
      lsum[i] += cls[qg][i][q32];
      float inv[16];
#pragma unroll
      for (int r = 0; r < 16; r++) {
        const int qv = (r & 3) + 8 * (r >> 2) + 4 * h;
        inv[r] = 1.f / __shfl(lsum[i], qv);
      }
#pragma unroll
      for (int db = 0; db < 2; db++) {
#pragma unroll
        for (int r = 0; r < 16; r++) {
          const int qv = (r & 3) + 8 * (r >> 2) + 4 * h;
          AO[(size_t)(b * 2048 + q0 + i * 32 + qv) * 512 + hd * 64 + db * 32 + q32] =
              (bf16)(oacc[i][db][r] * inv[r]);
        }
      }
    }
  }
}

// ---------------- launch ----------------
extern "C" void kernel_launch(void* const* d_in, const int* in_sizes, int n_in,
                              void* d_out, int out_size, void* d_ws, size_t ws_size,
                              hipStream_t stream) {
  (void)in_sizes; (void)n_in; (void)out_size; (void)ws_size;
  const float* x1 = (const float*)d_in[0];
  const float* x2 = (const float*)d_in[1];
  const float* Wq = (const float*)d_in[2];
  const float* Wk = (const float*)d_in[3];
  const float* Wv = (const float*)d_in[4];
  const float* Wo = (const float*)d_in[5];
  const float* bo = (const float*)d_in[6];

  uint8_t* ws = (uint8_t*)d_ws;
  bf16* AO  = (bf16*)(ws + 0);          // [8192][512]
  bf16* Qws = (bf16*)(ws + 18874368);   // [b][h][s][64]
  bf16* Kws = (bf16*)(ws + 27262976);   // [b][h][s][64]
  bf16* Vtw = (bf16*)(ws + 35651584);   // [b][h][64][s]

  qkv128_kernel<<<dim3(64, 12), 256, 0, stream>>>(x1, x2, Wq, Wk, Wv, Qws, Kws, Vtw);

  attn_kernel<<<256, 512, 0, stream>>>(Qws, Kws, Vtw, AO);

  outproj_kernel<<<dim3(64, 8), 256, 0, stream>>>(AO, Wo, (float*)d_out, bo);
}

// Round 24
// 91.065 us; speedup vs baseline: 1.0255x; 1.0225x over previous
//
#include <hip/hip_runtime.h>
#include <stdint.h>

typedef __bf16 bf16;
typedef __bf16 bf16x8 __attribute__((ext_vector_type(8)));
typedef __bf16 bf16x4 __attribute__((ext_vector_type(4)));
typedef float f32x4 __attribute__((ext_vector_type(4)));
typedef float f32x16 __attribute__((ext_vector_type(16)));
typedef uint32_t u32x4 __attribute__((ext_vector_type(4)));

#define MFMA16x16x32(A, B, C) __builtin_amdgcn_mfma_f32_16x16x32_bf16((A), (B), (C), 0, 0, 0)
#define MFMA32x32x16(A, B, C) __builtin_amdgcn_mfma_f32_32x32x16_bf16((A), (B), (C), 0, 0, 0)
#define SBAR() do { __builtin_amdgcn_s_barrier(); __builtin_amdgcn_sched_barrier(0); } while (0)

__device__ __forceinline__ void gload_lds16(const void* g, void* l) {
  __builtin_amdgcn_global_load_lds((const __attribute__((address_space(1))) void*)g,
                                   (__attribute__((address_space(3))) void*)l,
                                   16, 0, 0);
}

__device__ __forceinline__ float fexp2(float x) { return __builtin_amdgcn_exp2f(x); }

__device__ __forceinline__ uint32_t cvtpk(float a, float b) {
  uint32_t r;
  asm("v_cvt_pk_bf16_f32 %0, %1, %2" : "=v"(r) : "v"(a), "v"(b));
  return r;
}
__device__ __forceinline__ void plswap(uint32_t& a, uint32_t& b) {
  asm volatile("v_permlane32_swap_b32 %0, %1" : "+v"(a), "+v"(b));
}

__device__ __forceinline__ bf16x8 cvt8(float4 a, float4 b) {
  bf16x8 o;
  o[0] = (bf16)a.x; o[1] = (bf16)a.y; o[2] = (bf16)a.z; o[3] = (bf16)a.w;
  o[4] = (bf16)b.x; o[5] = (bf16)b.y; o[6] = (bf16)b.z; o[7] = (bf16)b.w;
  return o;
}

// ---------------- QKV projection with FUSED f32->bf16 cast (validated r15/r18/r19) ---
__global__ __launch_bounds__(256, 2) void qkv128_kernel(
    const float* __restrict__ x1, const float* __restrict__ x2,
    const float* __restrict__ Wq, const float* __restrict__ Wk,
    const float* __restrict__ Wv, bf16* __restrict__ Qw,
    bf16* __restrict__ Kw, bf16* __restrict__ Vtw) {
  __shared__ bf16 As[3][128 * 32];
  __shared__ bf16 Bs[3][128 * 32];
  const int tid = threadIdx.x;
  const int w = tid >> 6, l = tid & 63;
  const int wr = w >> 1, wc = w & 1;
  const int lr = l & 15, lg = l >> 4;
  const int bm = blockIdx.x, bn = blockIdx.y;
  const int K = 512;
  const int sel = bn >> 2, wn = bn & 3;

  const float* A = (sel == 0) ? x1 : x2;
  const float* B = ((sel == 0) ? Wq : (sel == 1) ? Wk : Wv) + (size_t)wn * 128 * K;

  const int c_row = l >> 2;
  const int c_s = l & 3;
  const int sw = (c_s ^ (c_row & 3)) * 8;

  float4 ra0[2][2], ra1[2][2], rb0[2][2], rb1[2][2];

#define ISSUE(t, ra, rb)                                                          \
  {                                                                               \
    _Pragma("unroll") for (int i = 0; i < 2; i++) {                               \
      const int q = w + i * 4;                                                    \
      const float* pa = A + (size_t)(bm * 128 + q * 16 + c_row) * K + (t) * 32 + c_s * 8; \
      ra[i][0] = *reinterpret_cast<const float4*>(pa);                            \
      ra[i][1] = *reinterpret_cast<const float4*>(pa + 4);                        \
      const float* pb = B + (size_t)(q * 16 + c_row) * K + (t) * 32 + c_s * 8;    \
      rb[i][0] = *reinterpret_cast<const float4*>(pb);                            \
      rb[i][1] = *reinterpret_cast<const float4*>(pb + 4);                        \
    }                                                                             \
  }
#define COMMIT(bb, ra, rb)                                                        \
  {                                                                               \
    _Pragma("unroll") for (int i = 0; i < 2; i++) {                               \
      const int q = w + i * 4;                                                    \
      *reinterpret_cast<bf16x8*>(&As[bb][q * 512 + c_row * 32 + sw]) = cvt8(ra[i][0], ra[i][1]); \
      *reinterpret_cast<bf16x8*>(&Bs[bb][q * 512 + c_row * 32 + sw]) = cvt8(rb[i][0], rb[i][1]); \
    }                                                                             \
  }

  f32x4 acc[4][4] = {};
  const int swz = (lr & 3) * 8;

  auto compute = [&](int cur) {
    bf16x8 a[4], b[4];
#pragma unroll
    for (int mi = 0; mi < 4; mi++)
      a[mi] = *reinterpret_cast<const bf16x8*>(
          &As[cur][(wr * 64 + mi * 16 + lr) * 32 + (lg * 8 ^ swz)]);
#pragma unroll
    for (int ni = 0; ni < 4; ni++)
      b[ni] = *reinterpret_cast<const bf16x8*>(
          &Bs[cur][(wc * 64 + ni * 16 + lr) * 32 + (lg * 8 ^ swz)]);
#pragma unroll
    for (int mi = 0; mi < 4; mi++)
#pragma unroll
      for (int ni = 0; ni < 4; ni++)
        acc[mi][ni] = MFMA16x16x32(a[mi], b[ni], acc[mi][ni]);
  };

  ISSUE(0, ra0, rb0);
  ISSUE(1, ra1, rb1);
  asm volatile("s_waitcnt vmcnt(8)" ::: "memory");
  COMMIT(0, ra0, rb0);
  asm volatile("s_waitcnt lgkmcnt(0)" ::: "memory");
  SBAR();

  const int NT = 16;
  for (int t = 0; t < NT; t += 2) {
    if (t + 2 < NT) ISSUE(t + 2, ra0, rb0);
    compute(t % 3);
    {
      if (t + 2 < NT) asm volatile("s_waitcnt vmcnt(8)" ::: "memory");
      else            asm volatile("s_waitcnt vmcnt(0)" ::: "memory");
      COMMIT((t + 1) % 3, ra1, rb1);
      asm volatile("s_waitcnt lgkmcnt(0)" ::: "memory");
      SBAR();
    }
    if (t + 3 < NT) ISSUE(t + 3, ra1, rb1);
    compute((t + 1) % 3);
    if (t + 2 < NT) {
      if (t + 3 < NT) asm volatile("s_waitcnt vmcnt(8)" ::: "memory");
      else            asm volatile("s_waitcnt vmcnt(0)" ::: "memory");
      COMMIT((t + 2) % 3, ra0, rb0);
      asm volatile("s_waitcnt lgkmcnt(0)" ::: "memory");
      SBAR();
    }
  }
#undef ISSUE
#undef COMMIT

  const float scale = (sel == 0) ? 0.18033688011112f : 1.0f;
#pragma unroll
  for (int mi = 0; mi < 4; mi++) {
    const int m0 = bm * 128 + wr * 64 + mi * 16 + lg * 4;
#pragma unroll
    for (int ni = 0; ni < 4; ni++) {
      const int gn = wn * 128 + wc * 64 + ni * 16 + lr;
      if (sel < 2) {
        bf16* dst = (sel == 0) ? Qw : Kw;
#pragma unroll
        for (int r = 0; r < 4; r++) {
          const int m = m0 + r;
          size_t d = (size_t)((m >> 11) * 8 + (gn >> 6)) * 131072 + (size_t)(m & 2047) * 64 + (gn & 63);
          dst[d] = (bf16)(acc[mi][ni][r] * scale);
        }
      } else {
        bf16x4 pv;
#pragma unroll
        for (int r = 0; r < 4; r++) pv[r] = (bf16)acc[mi][ni][r];
        size_t base = ((size_t)(m0 >> 11) * 512 + gn) * 2048 + (m0 & 2047);
        *reinterpret_cast<bf16x4*>(Vtw + base) = pv;
      }
    }
  }
}

// ---------------- out projection (validated) ----------------
__global__ __launch_bounds__(256, 4) void outproj_kernel(
    const bf16* __restrict__ A0, const float* __restrict__ W0,
    float* __restrict__ C0, const float* __restrict__ bias) {
  __shared__ bf16 As[3][128 * 32];
  __shared__ bf16 Bs[2][64 * 32];
  const int tid = threadIdx.x;
  const int w = tid >> 6, l = tid & 63;
  const int wr = w >> 1, wc = w & 1;
  const int lr = l & 15, lg = l >> 4;
  const int bm = blockIdx.x, bn = blockIdx.y;
  const int K = 512;

  const float* Bf = W0 + (size_t)bn * 64 * K;
  const int c_row = l >> 2;
  const int c_s = l & 3;
  const int sw = (c_s ^ (c_row & 3)) * 8;

  float4 lb[2][2];
  auto issue_A = [&](int t, int bb) {
#pragma unroll
    for (int i = 0; i < 2; i++) {
      const int q = w + i * 4;
      gload_lds16(A0 + (size_t)(bm * 128 + q * 16 + c_row) * K + t * 32 + sw, &As[bb][q * 512]);
    }
  };
  auto issue_B = [&](int t, int s) {
    const float* pb = Bf + (size_t)(w * 16 + c_row) * K + t * 32 + c_s * 8;
    lb[s][0] = *reinterpret_cast<const float4*>(pb);
    lb[s][1] = *reinterpret_cast<const float4*>(pb + 4);
  };
  auto commit_B = [&](int s, int bb) {
    *reinterpret_cast<bf16x8*>(&Bs[bb][w * 512 + c_row * 32 + sw]) = cvt8(lb[s][0], lb[s][1]);
  };

  f32x4 acc[4][2] = {};
  const int swz = (lr & 3) * 8;

  issue_A(0, 0); issue_B(0, 0);
  issue_A(1, 1); issue_B(1, 1);
  asm volatile("s_waitcnt vmcnt(4)" ::: "memory");
  commit_B(0, 0);
  asm volatile("s_waitcnt lgkmcnt(0)" ::: "memory");
  SBAR();

  const int NT = 16;
  for (int t = 0; t < NT; t++) {
    if (t + 2 < NT) { issue_A(t + 2, (t + 2) % 3); issue_B(t + 2, t & 1); }

    bf16x8 a[4], b[2];
    const int cur = t % 3;
#pragma unroll
    for (int mi = 0; mi < 4; mi++)
      a[mi] = *reinterpret_cast<const bf16x8*>(
          &As[cur][(wr * 64 + mi * 16 + lr) * 32 + (lg * 8 ^ swz)]);
#pragma unroll
    for (int ni = 0; ni < 2; ni++)
      b[ni] = *reinterpret_cast<const bf16x8*>(
          &Bs[t & 1][(wc * 32 + ni * 16 + lr) * 32 + (lg * 8 ^ swz)]);
#pragma unroll
    for (int mi = 0; mi < 4; mi++)
#pragma unroll
      for (int ni = 0; ni < 2; ni++)
        acc[mi][ni] = MFMA16x16x32(a[mi], b[ni], acc[mi][ni]);

    if (t + 1 < NT) {
      if (t + 2 < NT) asm volatile("s_waitcnt vmcnt(4)" ::: "memory");
      else            asm volatile("s_waitcnt vmcnt(0)" ::: "memory");
      commit_B((t + 1) & 1, (t + 1) & 1);
      asm volatile("s_waitcnt lgkmcnt(0)" ::: "memory");
      SBAR();
    }
  }

#pragma unroll
  for (int mi = 0; mi < 4; mi++) {
    const int m0 = bm * 128 + wr * 64 + mi * 16 + lg * 4;
#pragma unroll
    for (int ni = 0; ni < 2; ni++) {
      const int gn = bn * 64 + wc * 32 + ni * 16 + lr;
      const float bv = bias[gn];
#pragma unroll
      for (int r = 0; r < 4; r++)
        C0[(size_t)(m0 + r) * 512 + gn] = acc[mi][ni][r] + bv;
    }
  }
}

// ---------------- flash attention: r19 + tree-reduced lsum ----------------
// Block: 512 thr = 8 waves = 4 q-groups(64 q) x 2 kv-halves; 256 q/block; grid 256.
// Ring-4, TWO tiles per barrier interval, full vmcnt(0) drain before every barrier.
// Change vs r19: lsum accumulation tree-reduced (16-deep serial fadd chain -> 5-deep;
// pure FP reassociation, invisible at bf16 output precision).
// Excluded by experiment: counted vmcnt (r16/r17), ring-8 (r20 spill), setprio (r15),
// KVBLK=128 (r16), direct-global K/V (r9), interleaved staging (r22 neutral).
__global__ __launch_bounds__(512, 1) void attn_kernel(
    const bf16* __restrict__ Q, const bf16* __restrict__ Kk,
    const bf16* __restrict__ Vt, bf16* __restrict__ AO) {
  __shared__ bf16 KV[2][4][64 * 64];  // [K|V][ring4][tile] = 64KB
  __shared__ float cls[4][2][32];     // lsum combine

  const int tid = threadIdx.x;
  const int w = tid >> 6, l = tid & 63;  // w 0..7
  const int q32 = l & 31;
  const int h = l >> 5;
  const int qg = w >> 1, kvh = w & 1;
  const int l7 = l & 7;

  // XCD-aware decode: grid 256, lin&7 = XCD; 4 bh per XCD -> K/V L2-resident
  const int lin = blockIdx.x;
  const int xcd = lin & 7;
  const int m = lin >> 3;            // 0..31
  const int bh = xcd * 4 + (m & 3);
  const int qb = m >> 2;             // 0..7
  const int b = bh >> 3, hd = bh & 7;

  const bf16* Qb = Q + (size_t)bh * 131072;
  const bf16* Kb = Kk + (size_t)bh * 131072;
  const bf16* Vb = Vt + (size_t)bh * 131072;

  const int q0 = qb * 256 + qg * 64;

  // Q B-frags: sub-block i, col q = q32, k = d = ks*16 + h*8 + j
  bf16x8 qf[2][4];
#pragma unroll
  for (int i = 0; i < 2; i++)
#pragma unroll
    for (int ks = 0; ks < 4; ks++)
      qf[i][ks] = *reinterpret_cast<const bf16x8*>(
          Qb + (size_t)(q0 + i * 32 + q32) * 64 + ks * 16 + h * 8);

  // staging: wave w stages K-chunk w and V-chunk w (8 rows x 64 each, 1KB)
  const int crow = l >> 3;
  const int scol = ((l & 7) ^ crow) * 8;
  auto stage = [&](int kv0, int bb) {
    const int row = w * 8 + crow;
    gload_lds16(Kb + (size_t)(kv0 + row) * 64 + scol, &KV[0][bb][w * 512]);
    gload_lds16(Vb + (size_t)row * 2048 + kv0 + scol, &KV[1][bb][w * 512]);
  };

  f32x16 oacc[2][2] = {};  // [i][db]
  float lsum[2] = {0.f, 0.f};

  // per-64kv-tile compute (r19-exact indexing; lsum tree-reduced)
  auto tilebody = [&](int cur) {
    bf16x8 kb[4];
#pragma unroll
    for (int ks = 0; ks < 4; ks++)
      kb[ks] = *reinterpret_cast<const bf16x8*>(
          &KV[0][cur][(kvh * 32 + q32) * 64 + (((ks * 2 + h) ^ l7) * 8)]);

    bf16x8 pa[2][2];
#pragma unroll
    for (int i = 0; i < 2; i++) {
      f32x16 st = {};
#pragma unroll
      for (int ks = 0; ks < 4; ks++)
        st = MFMA32x32x16(kb[ks], qf[i][ks], st);

      float e[16];
#pragma unroll
      for (int r = 0; r < 16; r++) e[r] = fexp2(st[r]);
      // tree-reduce (5-deep dependency instead of 16-deep serial chain)
      float s0 = (e[0] + e[1]) + (e[2] + e[3]);
      float s1 = (e[4] + e[5]) + (e[6] + e[7]);
      float s2 = (e[8] + e[9]) + (e[10] + e[11]);
      float s3 = (e[12] + e[13]) + (e[14] + e[15]);
      lsum[i] += (s0 + s1) + (s2 + s3);
      uint32_t Qp[8];
#pragma unroll
      for (int p2 = 0; p2 < 8; p2++) Qp[p2] = cvtpk(e[2 * p2], e[2 * p2 + 1]);
      plswap(Qp[0], Qp[2]);
      plswap(Qp[1], Qp[3]);
      plswap(Qp[4], Qp[6]);
      plswap(Qp[5], Qp[7]);
      pa[i][0] = __builtin_bit_cast(bf16x8, (u32x4){Qp[0], Qp[1], Qp[2], Qp[3]});
      pa[i][1] = __builtin_bit_cast(bf16x8, (u32x4){Qp[4], Qp[5], Qp[6], Qp[7]});
    }

    bf16x8 vb[2][2];
#pragma unroll
    for (int kst = 0; kst < 2; kst++)
#pragma unroll
      for (int db = 0; db < 2; db++)
        vb[kst][db] = *reinterpret_cast<const bf16x8*>(
            &KV[1][cur][(db * 32 + q32) * 64 + (((kvh * 4 + kst * 2 + h) ^ l7) * 8)]);

#pragma unroll
    for (int i = 0; i < 2; i++)
#pragma unroll
      for (int kst = 0; kst < 2; kst++)
#pragma unroll
        for (int db = 0; db < 2; db++)
          oacc[i][db] = MFMA32x32x16(pa[i][kst], vb[kst][db], oacc[i][db]);
  };

  // prologue: stage tiles 0,1; full drain
  stage(0, 0);
  stage(64, 1);
  asm volatile("s_waitcnt vmcnt(0)" ::: "memory");
  SBAR();

  for (int p = 0; p < 16; p++) {
    const int t0 = 2 * p, t1 = 2 * p + 1;
    if (p < 15) {
      stage((t0 + 2) * 64, (t0 + 2) & 3);
      stage((t1 + 2) * 64, (t1 + 2) & 3);
    }
    tilebody(t0 & 3);
    tilebody(t1 & 3);
    if (p < 15) {
      asm volatile("s_waitcnt vmcnt(0) lgkmcnt(0)" ::: "memory");
      SBAR();
    }
  }

  // lanes l and l+32 hold partials of the same q (within this wave's kv-half)
#pragma unroll
  for (int i = 0; i < 2; i++) lsum[i] += __shfl_xor(lsum[i], 32);

  // combine kv-halves via dead K/V LDS (first 32KB), two passes (i=0, i=1)
  float* cb = (float*)&KV[0][0][0];
  __syncthreads();
  if (kvh == 1 && l < 32) {
    cls[qg][0][q32] = lsum[0];
    cls[qg][1][q32] = lsum[1];
  }
#pragma unroll
  for (int i = 0; i < 2; i++) {
    if (kvh == 1) {
#pragma unroll
      for (int db = 0; db < 2; db++)
#pragma unroll
        for (int r = 0; r < 16; r++)
          cb[((qg * 2 + db) * 16 + r) * 64 + l] = oacc[i][db][r];
    }
    __syncthreads();
    if (kvh == 0) {
#pragma unroll
      for (int db = 0; db < 2; db++)
#pragma unroll
        for (int r = 0; r < 16; r++)
          oacc[i][db][r] += cb[((qg * 2 + db) * 16 + r) * 64 + l];
    }
    __syncthreads();
  }

  if (kvh == 0) {
#pragma unroll
    for (int i = 0; i < 2; i++) {
      lsum[i] += cls[qg][i][q32];
      float inv[16];
#pragma unroll
      for (int r = 0; r < 16; r++) {
        const int qv = (r & 3) + 8 * (r >> 2) + 4 * h;
        inv[r] = 1.f / __shfl(lsum[i], qv);
      }
#pragma unroll
      for (int db = 0; db < 2; db++) {
#pragma unroll
        for (int r = 0; r < 16; r++) {
          const int qv = (r & 3) + 8 * (r >> 2) + 4 * h;
          AO[(size_t)(b * 2048 + q0 + i * 32 + qv) * 512 + hd * 64 + db * 32 + q32] =
              (bf16)(oacc[i][db][r] * inv[r]);
        }
      }
    }
  }
}

// ---------------- launch ----------------
extern "C" void kernel_launch(void* const* d_in, const int* in_sizes, int n_in,
                              void* d_out, int out_size, void* d_ws, size_t ws_size,
                              hipStream_t stream) {
  (void)in_sizes; (void)n_in; (void)out_size; (void)ws_size;
  const float* x1 = (const float*)d_in[0];
  const float* x2 = (const float*)d_in[1];
  const float* Wq = (const float*)d_in[2];
  const float* Wk = (const float*)d_in[3];
  const float* Wv = (const float*)d_in[4];
  const float* Wo = (const float*)d_in[5];
  const float* bo = (const float*)d_in[6];

  uint8_t* ws = (uint8_t*)d_ws;
  bf16* AO  = (bf16*)(ws + 0);          // [8192][512]
  bf16* Qws = (bf16*)(ws + 18874368);   // [b][h][s][64]
  bf16* Kws = (bf16*)(ws + 27262976);   // [b][h][s][64]
  bf16* Vtw = (bf16*)(ws + 35651584);   // [b][h][64][s]

  qkv128_kernel<<<dim3(64, 12), 256, 0, stream>>>(x1, x2, Wq, Wk, Wv, Qws, Kws, Vtw);

  attn_kernel<<<256, 512, 0, stream>>>(Qws, Kws, Vtw, AO);

  outproj_kernel<<<dim3(64, 8), 256, 0, stream>>>(AO, Wo, (float*)d_out, bo);
}